// Round 7
// baseline (159.837 us; speedup 1.0000x reference)
//
#include <hip/hip_runtime.h>
#include <hip/hip_bf16.h>

typedef __attribute__((ext_vector_type(8))) short bf16x8;
typedef __attribute__((ext_vector_type(4))) float f32x4;
typedef __attribute__((ext_vector_type(4))) short s16x4;

#define M_DIM 4096   // B*S = 2*2048
#define N_DIM 4096   // D_out
#define K_DIM 4096   // D_in
#define R_DIM 4

__device__ __forceinline__ short to_bf16(float f) {
    __hip_bfloat16 h = __float2bfloat16(f);
    return *reinterpret_cast<short*>(&h);
}

// ---------------------------------------------------------------------------
// Kernel 1: tB[r][i] = tanh(scale_B[r,i]); tAg[o][r] = tanh(scale_A[o,r])*g[r]
// ---------------------------------------------------------------------------
__global__ __launch_bounds__(256)
void k_prep(const float* __restrict__ sA, const float* __restrict__ sB,
            const float* __restrict__ g, float* __restrict__ tB,
            float* __restrict__ tAg) {
    int i = blockIdx.x * 256 + threadIdx.x;
    if (i < R_DIM * K_DIM) {
        tB[i] = tanhf(sB[i]);
    } else {
        int j = i - R_DIM * K_DIM;   // j = o*4 + r
        tAg[j] = tanhf(sA[j]) * g[j & 3];
    }
}

// ---------------------------------------------------------------------------
// Kernel 2: x_bf16[m,k] = (bf16) x[m,k]
// ---------------------------------------------------------------------------
__global__ __launch_bounds__(256)
void k_xcast(const float* __restrict__ x, __hip_bfloat16* __restrict__ xb) {
    const size_t i = ((size_t)blockIdx.x * 256 + threadIdx.x) << 3;
    float4 u = *(const float4*)&x[i];
    float4 v = *(const float4*)&x[i + 4];
    bf16x8 pk;
    pk[0] = to_bf16(u.x); pk[1] = to_bf16(u.y);
    pk[2] = to_bf16(u.z); pk[3] = to_bf16(u.w);
    pk[4] = to_bf16(v.x); pk[5] = to_bf16(v.y);
    pk[6] = to_bf16(v.z); pk[7] = to_bf16(v.w);
    *(bf16x8*)&xb[i] = pk;
}

// ---------------------------------------------------------------------------
// Kernel 3: W_eff[o,i] = weight[o,i] * sum_r tAg[o,r]*tB[r,i]  -> bf16
// ---------------------------------------------------------------------------
__global__ __launch_bounds__(256)
void k_weff(const float* __restrict__ w, const float* __restrict__ tB,
            const float* __restrict__ tAg, __hip_bfloat16* __restrict__ weff) {
    const int o = blockIdx.x;
    const float a0 = tAg[o * 4 + 0];
    const float a1 = tAg[o * 4 + 1];
    const float a2 = tAg[o * 4 + 2];
    const float a3 = tAg[o * 4 + 3];
#pragma unroll
    for (int it = 0; it < 4; ++it) {
        const int i = (it * 256 + (int)threadIdx.x) << 2;
        float4 wv = *(const float4*)&w[(size_t)o * K_DIM + i];
        float4 b0 = *(const float4*)&tB[0 * K_DIM + i];
        float4 b1 = *(const float4*)&tB[1 * K_DIM + i];
        float4 b2 = *(const float4*)&tB[2 * K_DIM + i];
        float4 b3 = *(const float4*)&tB[3 * K_DIM + i];
        float s0 = a0 * b0.x + a1 * b1.x + a2 * b2.x + a3 * b3.x;
        float s1 = a0 * b0.y + a1 * b1.y + a2 * b2.y + a3 * b3.y;
        float s2 = a0 * b0.z + a1 * b1.z + a2 * b2.z + a3 * b3.z;
        float s3 = a0 * b0.w + a1 * b1.w + a2 * b2.w + a3 * b3.w;
        s16x4 pk;
        pk[0] = to_bf16(wv.x * s0);
        pk[1] = to_bf16(wv.y * s1);
        pk[2] = to_bf16(wv.z * s2);
        pk[3] = to_bf16(wv.w * s3);
        *(s16x4*)&weff[(size_t)o * K_DIM + i] = pk;
    }
}

// ---------------------------------------------------------------------------
// Kernel 4: out = x_bf16 @ weff^T + bias — 256x256 8-phase, ONE barrier per
// phase.  16x16x32 core, staging/swizzle/FRAG identical to the verified
// round-3 kernel.  Phase = { reads; stage 1 half-tile; [vmcnt(2) @p4,p8];
// s_barrier; lgkmcnt(0); sched_barrier(0); setprio(1) 16xMFMA setprio(0) }.
//
// Stage slots (iter i: d0 reads k=2i at p1-p4, d1 reads k=2i+1 at p5-p8):
//   p1: B1.h1 <- k(2i+1)   p2: A1.h0 <- k(2i+1)   p3: A1.h1 <- k(2i+1)
//   p4: B0.h0 <- k(2i+2)+VM2               p5: B0.h1 <- k(2i+2)
//   p6: A0.h0 <- k(2i+2)   p7: A0.h1 <- k(2i+2)   p8: B1.h0 <- k(2i+3)+VM2
// Hazard ledger (single-barrier safety = restage >= 2 phases after last read,
// because each phase's post-barrier lgkmcnt(0) precedes the NEXT barrier):
//   B1 last read p5  -> staged p8/p1'  (gap 3/4)
//   A1 last read p8  -> staged p2'/p3' (gap 2/3)
//   B0 last read p1  -> staged p4/p5   (gap 3/4)
//   A0 last read p4  -> staged p6/p7   (gap 2/3)
// Visibility: VM2@p4 completes {B1.h0(p8'),B1.h1(p1),A1(p2,p3)} for p5 reads;
//             VM2@p8 completes {B0(p4,p5),A0(p6,p7)} for p1' reads.
// ---------------------------------------------------------------------------
#define MFMA_N(q, n, bA, bB) \
    acc[2*(q)][(n)]   = __builtin_amdgcn_mfma_f32_16x16x32_bf16(a0, bA, acc[2*(q)][(n)],   0, 0, 0); \
    acc[2*(q)][(n)]   = __builtin_amdgcn_mfma_f32_16x16x32_bf16(a1, bB, acc[2*(q)][(n)],   0, 0, 0); \
    acc[2*(q)+1][(n)] = __builtin_amdgcn_mfma_f32_16x16x32_bf16(a2, bA, acc[2*(q)+1][(n)], 0, 0, 0); \
    acc[2*(q)+1][(n)] = __builtin_amdgcn_mfma_f32_16x16x32_bf16(a3, bB, acc[2*(q)+1][(n)], 0, 0, 0);

#define READ_A(d, q) \
    { const int Ab_ = ((d) * 2 + wr) * 8192; \
      a0 = FRAG(Ab_, (2*(q))   * 16 + l15, cb0); \
      a1 = FRAG(Ab_, (2*(q))   * 16 + l15, cb1); \
      a2 = FRAG(Ab_, (2*(q)+1) * 16 + l15, cb0); \
      a3 = FRAG(Ab_, (2*(q)+1) * 16 + l15, cb1); }

#define READ_B(d) \
    { const int Bb_ = 32768 + ((d) * 2 + (wc >> 1)) * 8192; \
      b0 = FRAG(Bb_, br0, cb0); b1 = FRAG(Bb_, br0, cb1); \
      b2 = FRAG(Bb_, br1, cb0); b3 = FRAG(Bb_, br1, cb1); \
      b4 = FRAG(Bb_, br2, cb0); b5 = FRAG(Bb_, br2, cb1); \
      b6 = FRAG(Bb_, br3, cb0); b7 = FRAG(Bb_, br3, cb1); }

#define VM2 asm volatile("s_waitcnt vmcnt(2)" ::: "memory")

#define PH(d, q, READS_STMT, STAGE_STMT, VM_STMT) \
    { READS_STMT; \
      STAGE_STMT; \
      VM_STMT; \
      __builtin_amdgcn_s_barrier(); \
      asm volatile("s_waitcnt lgkmcnt(0)" ::: "memory"); \
      __builtin_amdgcn_sched_barrier(0); \
      __builtin_amdgcn_s_setprio(1); \
      MFMA_N(q, 0, b0, b1); MFMA_N(q, 1, b2, b3); \
      MFMA_N(q, 2, b4, b5); MFMA_N(q, 3, b6, b7); \
      __builtin_amdgcn_s_setprio(0); }

__global__ __launch_bounds__(512)
void k_gemm8(const __hip_bfloat16* __restrict__ xb,
             const __hip_bfloat16* __restrict__ weff,
             const float* __restrict__ bias, float* __restrict__ out) {
    __shared__ short lds[65536];   // A halves: [0,32768) ; B halves: [32768,65536)

    const int tid  = threadIdx.x;
    const int lane = tid & 63;
    const int wid  = tid >> 6;
    const int wr   = wid >> 2;           // wave M row 0..1  (128 rows each)
    const int wc   = wid & 3;            // wave N col 0..3  (64 cols each)
    const int l15  = lane & 15;
    const int cb0  = (lane >> 4) << 4;   // ksub0 fragment col-byte
    const int cb1  = cb0 + 64;           // ksub1

    // XCD-aware bijective swizzle: nwg=256, 256 % 8 == 0
    const int bid = blockIdx.x;
    const int swz = (bid & 7) * 32 + (bid >> 3);
    const int m0g = (swz >> 4) << 8;
    const int n0g = (swz & 15) << 8;

    const int br0 = (wc & 1) * 64 + 0  + l15;
    const int br1 = (wc & 1) * 64 + 16 + l15;
    const int br2 = (wc & 1) * 64 + 32 + l15;
    const int br3 = (wc & 1) * 64 + 48 + l15;

    auto STAGE = [&](const __hip_bfloat16* __restrict__ src, int gr0, int k0, int base) {
#pragma unroll
        for (int p = 0; p < 2; ++p) {
            const int P    = p * 8192 + tid * 16;            // phys byte in half
            const int row  = P >> 7;
            const int colb = (P & 127) ^ ((row & 7) << 4);   // inverse-swizzled src
            const __hip_bfloat16* g = src + ((size_t)(gr0 + row) << 12) + (k0 + (colb >> 1));
            __builtin_amdgcn_global_load_lds(
                (const __attribute__((address_space(1))) void*)g,
                (__attribute__((address_space(3))) void*)&lds[base + (P >> 1)],
                16, 0, 0);
        }
    };

    auto FRAG = [&](int base, int row, int cb) -> bf16x8 {
        const int byte = ((((row << 7) + cb) ^ ((row & 7) << 4))) + base * 2;
        return *(const bf16x8*)((const char*)lds + byte);
    };

    f32x4 acc[8][4] = {};
    bf16x8 a0, a1, a2, a3, b0, b1, b2, b3, b4, b5, b6, b7;

    // prologue = "previous iteration's p4..p8 stages":
    //   B0 <- k0, A0 <- k0, B1.h0 <- k1   (10 loads); vmcnt(2) leaves B1.h0
    STAGE(weff, n0g,       0,  32768);
    STAGE(weff, n0g + 128, 0,  40960);
    STAGE(xb,   m0g,       0,  0);
    STAGE(xb,   m0g + 128, 0,  8192);
    STAGE(weff, n0g,       64, 49152);
    VM2;
    __builtin_amdgcn_s_barrier();
    __builtin_amdgcn_sched_barrier(0);

    for (int i = 0; i < 32; ++i) {
        const int t1k = (2 * i + 1) * 64;
        const int kA  = (2 * i + 2 < 64 ? 2 * i + 2 : 63) * 64;
        const int kB  = (2 * i + 3 < 64 ? 2 * i + 3 : 63) * 64;

        // ---- K-tile d0 ----
        PH(0, 0, READ_A(0, 0); READ_B(0), STAGE(weff, n0g + 128, t1k, 57344), );
        PH(0, 1, READ_A(0, 1),            STAGE(xb,   m0g,       t1k, 16384), );
        PH(0, 2, READ_A(0, 2),            STAGE(xb,   m0g + 128, t1k, 24576), );
        PH(0, 3, READ_A(0, 3),            STAGE(weff, n0g,       kA,  32768), VM2);
        // ---- K-tile d1 ----
        PH(1, 0, READ_A(1, 0); READ_B(1), STAGE(weff, n0g + 128, kA,  40960), );
        PH(1, 1, READ_A(1, 1),            STAGE(xb,   m0g,       kA,  0), );
        PH(1, 2, READ_A(1, 2),            STAGE(xb,   m0g + 128, kA,  8192), );
        PH(1, 3, READ_A(1, 3),            STAGE(weff, n0g,       kB,  49152), VM2);
    }

    // epilogue: C/D map col=lane&15, row=(lane>>4)*4+j
#pragma unroll
    for (int n = 0; n < 4; ++n) {
        const int col = n0g + wc * 64 + n * 16 + l15;
        const float bv = bias[col];
#pragma unroll
        for (int m = 0; m < 8; ++m) {
            const int rbase = m0g + wr * 128 + m * 16 + ((lane >> 4) << 2);
#pragma unroll
            for (int j = 0; j < 4; ++j)
                out[(size_t)(rbase + j) * N_DIM + col] = acc[m][n][j] + bv;
        }
    }
}

// ---------------------------------------------------------------------------
extern "C" void kernel_launch(void* const* d_in, const int* in_sizes, int n_in,
                              void* d_out, int out_size, void* d_ws, size_t ws_size,
                              hipStream_t stream) {
    const float* x    = (const float*)d_in[0];  // [2,2048,4096]
    const float* w    = (const float*)d_in[1];  // [4096,4096]
    const float* bias = (const float*)d_in[2];  // [4096]
    const float* sA   = (const float*)d_in[3];  // [4096,4]
    const float* sB   = (const float*)d_in[4];  // [4,4096]
    const float* g    = (const float*)d_in[5];  // [4]
    float* out = (float*)d_out;

    // [weff bf16: 32MB][x_bf16: 32MB][tB f32: 64KB][tAg f32: 64KB]
    __hip_bfloat16* weff = (__hip_bfloat16*)d_ws;
    __hip_bfloat16* xb   = (__hip_bfloat16*)((char*)d_ws + (32ull << 20));
    float* tB  = (float*)((char*)d_ws + (64ull << 20));
    float* tAg = (float*)((char*)d_ws + (64ull << 20) + (R_DIM * K_DIM * 4));

    k_prep<<<dim3((2 * R_DIM * K_DIM) / 256), dim3(256), 0, stream>>>(sA, sB, g, tB, tAg);
    k_xcast<<<dim3((M_DIM * K_DIM) / (256 * 8)), dim3(256), 0, stream>>>(x, xb);
    k_weff<<<dim3(N_DIM), dim3(256), 0, stream>>>(w, tB, tAg, weff);
    k_gemm8<<<dim3((M_DIM / 256) * (N_DIM / 256)), dim3(512), 0, stream>>>(xb, weff, bias, out);
}

// Round 8
// 153.992 us; speedup vs baseline: 1.0380x; 1.0380x over previous
//
#include <hip/hip_runtime.h>
#include <hip/hip_bf16.h>

typedef __attribute__((ext_vector_type(8))) short bf16x8;
typedef __attribute__((ext_vector_type(4))) float f32x4;
typedef __attribute__((ext_vector_type(4))) short s16x4;

#define M_DIM 4096   // B*S = 2*2048
#define N_DIM 4096   // D_out
#define K_DIM 4096   // D_in
#define R_DIM 4

__device__ __forceinline__ short to_bf16(float f) {
    __hip_bfloat16 h = __float2bfloat16(f);
    return *reinterpret_cast<short*>(&h);
}

// ---------------------------------------------------------------------------
// Kernel 1: tB[r][i] = tanh(scale_B[r,i]); tAg[o][r] = tanh(scale_A[o,r])*g[r]
// ---------------------------------------------------------------------------
__global__ __launch_bounds__(256)
void k_prep(const float* __restrict__ sA, const float* __restrict__ sB,
            const float* __restrict__ g, float* __restrict__ tB,
            float* __restrict__ tAg) {
    int i = blockIdx.x * 256 + threadIdx.x;
    if (i < R_DIM * K_DIM) {
        tB[i] = tanhf(sB[i]);
    } else {
        int j = i - R_DIM * K_DIM;   // j = o*4 + r
        tAg[j] = tanhf(sA[j]) * g[j & 3];
    }
}

// ---------------------------------------------------------------------------
// Kernel 2: x_bf16[m,k] = (bf16) x[m,k]
// ---------------------------------------------------------------------------
__global__ __launch_bounds__(256)
void k_xcast(const float* __restrict__ x, __hip_bfloat16* __restrict__ xb) {
    const size_t i = ((size_t)blockIdx.x * 256 + threadIdx.x) << 3;
    float4 u = *(const float4*)&x[i];
    float4 v = *(const float4*)&x[i + 4];
    bf16x8 pk;
    pk[0] = to_bf16(u.x); pk[1] = to_bf16(u.y);
    pk[2] = to_bf16(u.z); pk[3] = to_bf16(u.w);
    pk[4] = to_bf16(v.x); pk[5] = to_bf16(v.y);
    pk[6] = to_bf16(v.z); pk[7] = to_bf16(v.w);
    *(bf16x8*)&xb[i] = pk;
}

// ---------------------------------------------------------------------------
// Kernel 3: W_eff[o,i] = weight[o,i] * sum_r tAg[o,r]*tB[r,i]  -> bf16
// ---------------------------------------------------------------------------
__global__ __launch_bounds__(256)
void k_weff(const float* __restrict__ w, const float* __restrict__ tB,
            const float* __restrict__ tAg, __hip_bfloat16* __restrict__ weff) {
    const int o = blockIdx.x;
    const float a0 = tAg[o * 4 + 0];
    const float a1 = tAg[o * 4 + 1];
    const float a2 = tAg[o * 4 + 2];
    const float a3 = tAg[o * 4 + 3];
#pragma unroll
    for (int it = 0; it < 4; ++it) {
        const int i = (it * 256 + (int)threadIdx.x) << 2;
        float4 wv = *(const float4*)&w[(size_t)o * K_DIM + i];
        float4 b0 = *(const float4*)&tB[0 * K_DIM + i];
        float4 b1 = *(const float4*)&tB[1 * K_DIM + i];
        float4 b2 = *(const float4*)&tB[2 * K_DIM + i];
        float4 b3 = *(const float4*)&tB[3 * K_DIM + i];
        float s0 = a0 * b0.x + a1 * b1.x + a2 * b2.x + a3 * b3.x;
        float s1 = a0 * b0.y + a1 * b1.y + a2 * b2.y + a3 * b3.y;
        float s2 = a0 * b0.z + a1 * b1.z + a2 * b2.z + a3 * b3.z;
        float s3 = a0 * b0.w + a1 * b1.w + a2 * b2.w + a3 * b3.w;
        s16x4 pk;
        pk[0] = to_bf16(wv.x * s0);
        pk[1] = to_bf16(wv.y * s1);
        pk[2] = to_bf16(wv.z * s2);
        pk[3] = to_bf16(wv.w * s3);
        *(s16x4*)&weff[(size_t)o * K_DIM + i] = pk;
    }
}

// ---------------------------------------------------------------------------
// Kernel 4: out = x_bf16 @ weff^T + bias — round-7 verified single-barrier
// 8-phase schedule, UNCHANGED.  This round: (a) LDS fragment reads via
// per-lane base pointers + compile-time immediates (proof: all rows used are
// (mult of 8)+l15, so XOR mask=(l15&7)<<4 is lane-constant; cb occupies bits
// 4-6 with no carries, so ((row<<7)+cb)^mask == row*128 + (cb^mask); cbs1 is
// precomputed as (cb0+64)^mask — the round-5 bug was applying +64 AFTER the
// XOR); (b) staging via 2 precomputed per-lane global base pointers; (c) MFMA
// phase order: 8 independent ops then their 8 partners (no back-to-back
// same-acc dependent pairs).
//
// Stage slots / hazard ledger identical to round 7 (verified):
//   p1: B1.h1  p2: A1.h0  p3: A1.h1  p4: B0.h0+VM2
//   p5: B0.h1  p6: A0.h0  p7: A0.h1  p8: B1.h0+VM2
// ---------------------------------------------------------------------------
#define MFMA(A, B, C) __builtin_amdgcn_mfma_f32_16x16x32_bf16(A, B, C, 0, 0, 0)

// LDS byte offsets (relative to LA0/LA1 or LB0/LB1 lane bases):
//   A(d,q,m):  d*32768 + q*4096 + m*2048     (m = 0/1)
//   B(d,n):    d*32768 + n*2048
#define RD_A(d, q) \
    a0 = *(const bf16x8*)(LA0 + (d)*32768 + (q)*4096); \
    a1 = *(const bf16x8*)(LA1 + (d)*32768 + (q)*4096); \
    a2 = *(const bf16x8*)(LA0 + (d)*32768 + (q)*4096 + 2048); \
    a3 = *(const bf16x8*)(LA1 + (d)*32768 + (q)*4096 + 2048);

#define RD_B(d) \
    b0 = *(const bf16x8*)(LB0 + (d)*32768 + 0); \
    b1 = *(const bf16x8*)(LB1 + (d)*32768 + 0); \
    b2 = *(const bf16x8*)(LB0 + (d)*32768 + 2048); \
    b3 = *(const bf16x8*)(LB1 + (d)*32768 + 2048); \
    b4 = *(const bf16x8*)(LB0 + (d)*32768 + 4096); \
    b5 = *(const bf16x8*)(LB1 + (d)*32768 + 4096); \
    b6 = *(const bf16x8*)(LB0 + (d)*32768 + 6144); \
    b7 = *(const bf16x8*)(LB1 + (d)*32768 + 6144);

#define VM2 asm volatile("s_waitcnt vmcnt(2)" ::: "memory")

#define PH(d, q, READS_STMT, STAGE_STMT, VM_STMT) \
    { READS_STMT; \
      STAGE_STMT; \
      VM_STMT; \
      __builtin_amdgcn_s_barrier(); \
      asm volatile("s_waitcnt lgkmcnt(0)" ::: "memory"); \
      __builtin_amdgcn_sched_barrier(0); \
      __builtin_amdgcn_s_setprio(1); \
      /* independent set: each acc touched once */ \
      acc[2*(q)][0]   = MFMA(a0, b0, acc[2*(q)][0]); \
      acc[2*(q)][1]   = MFMA(a0, b2, acc[2*(q)][1]); \
      acc[2*(q)][2]   = MFMA(a0, b4, acc[2*(q)][2]); \
      acc[2*(q)][3]   = MFMA(a0, b6, acc[2*(q)][3]); \
      acc[2*(q)+1][0] = MFMA(a2, b0, acc[2*(q)+1][0]); \
      acc[2*(q)+1][1] = MFMA(a2, b2, acc[2*(q)+1][1]); \
      acc[2*(q)+1][2] = MFMA(a2, b4, acc[2*(q)+1][2]); \
      acc[2*(q)+1][3] = MFMA(a2, b6, acc[2*(q)+1][3]); \
      /* partner set: >=8 issue slots after dependency */ \
      acc[2*(q)][0]   = MFMA(a1, b1, acc[2*(q)][0]); \
      acc[2*(q)][1]   = MFMA(a1, b3, acc[2*(q)][1]); \
      acc[2*(q)][2]   = MFMA(a1, b5, acc[2*(q)][2]); \
      acc[2*(q)][3]   = MFMA(a1, b7, acc[2*(q)][3]); \
      acc[2*(q)+1][0] = MFMA(a3, b1, acc[2*(q)+1][0]); \
      acc[2*(q)+1][1] = MFMA(a3, b3, acc[2*(q)+1][1]); \
      acc[2*(q)+1][2] = MFMA(a3, b5, acc[2*(q)+1][2]); \
      acc[2*(q)+1][3] = MFMA(a3, b7, acc[2*(q)+1][3]); \
      __builtin_amdgcn_s_setprio(0); }

__global__ __launch_bounds__(512)
void k_gemm8(const __hip_bfloat16* __restrict__ xb,
             const __hip_bfloat16* __restrict__ weff,
             const float* __restrict__ bias, float* __restrict__ out) {
    __shared__ short lds[65536];   // A halves: [0,32768) ; B halves: [32768,65536)

    const int tid  = threadIdx.x;
    const int lane = tid & 63;
    const int wid  = tid >> 6;
    const int wr   = wid >> 2;           // wave M row 0..1  (128 rows each)
    const int wc   = wid & 3;            // wave N col 0..3  (64 cols each)
    const int l15  = lane & 15;
    const int cb0  = (lane >> 4) << 4;   // ksub0 fragment col-byte (bits 4-5)

    // XCD-aware bijective swizzle: nwg=256, 256 % 8 == 0
    const int bid = blockIdx.x;
    const int swz = (bid & 7) * 32 + (bid >> 3);
    const int m0g = (swz >> 4) << 8;
    const int n0g = (swz & 15) << 8;

    // ---- per-lane LDS fragment base pointers (swizzle folded in) ----
    const int mask = (l15 & 7) << 4;          // = (row&7)<<4 for every row used
    const int cbs0 = cb0 ^ mask;              // pre-XOR, bits 4-6, no carries
    const int cbs1 = (cb0 + 64) ^ mask;
    const char* LAb = (const char*)lds + wr * 16384 + l15 * 128;
    const char* LA0 = LAb + cbs0;
    const char* LA1 = LAb + cbs1;
    const char* LBb = (const char*)lds + 65536 + (wc >> 1) * 16384 +
                      ((wc & 1) * 64 + l15) * 128;
    const char* LB0 = LBb + cbs0;
    const char* LB1 = LBb + cbs1;

    // ---- per-lane global staging base pointers (inverse-swizzled source) ----
    const int rowL  = tid >> 3;               // 0..63
    const int colbL = ((tid * 16) & 127) ^ ((rowL & 7) << 4);
    const __hip_bfloat16* gA = xb   + ((size_t)(m0g + rowL) << 12) + (colbL >> 1);
    const __hip_bfloat16* gB = weff + ((size_t)(n0g + rowL) << 12) + (colbL >> 1);
    // +262144 elems = +64 rows (pass 1); +524288 elems = +128 rows (half 1)

    auto STG = [&](const __hip_bfloat16* gbase, int k0, int dstShort) {
        __builtin_amdgcn_global_load_lds(
            (const __attribute__((address_space(1))) void*)(gbase + k0),
            (__attribute__((address_space(3))) void*)&lds[dstShort + tid * 8],
            16, 0, 0);
        __builtin_amdgcn_global_load_lds(
            (const __attribute__((address_space(1))) void*)(gbase + 262144 + k0),
            (__attribute__((address_space(3))) void*)&lds[dstShort + 4096 + tid * 8],
            16, 0, 0);
    };

    f32x4 acc[8][4] = {};
    bf16x8 a0, a1, a2, a3, b0, b1, b2, b3, b4, b5, b6, b7;

    // prologue: B0 <- k0, A0 <- k0, B1.h0 <- k1  (10 loads); VM2 leaves B1.h0
    STG(gB,          0,  32768);
    STG(gB + 524288, 0,  40960);
    STG(gA,          0,  0);
    STG(gA + 524288, 0,  8192);
    STG(gB,          64, 49152);
    VM2;
    __builtin_amdgcn_s_barrier();
    __builtin_amdgcn_sched_barrier(0);

    for (int i = 0; i < 32; ++i) {
        const int t1k = (2 * i + 1) * 64;
        const int kA  = (2 * i + 2 < 64 ? 2 * i + 2 : 63) * 64;
        const int kB  = (2 * i + 3 < 64 ? 2 * i + 3 : 63) * 64;

        // ---- K-tile d0 ----
        PH(0, 0, RD_A(0, 0); RD_B(0), STG(gB + 524288, t1k, 57344), );
        PH(0, 1, RD_A(0, 1),          STG(gA,          t1k, 16384), );
        PH(0, 2, RD_A(0, 2),          STG(gA + 524288, t1k, 24576), );
        PH(0, 3, RD_A(0, 3),          STG(gB,          kA,  32768), VM2);
        // ---- K-tile d1 ----
        PH(1, 0, RD_A(1, 0); RD_B(1), STG(gB + 524288, kA,  40960), );
        PH(1, 1, RD_A(1, 1),          STG(gA,          kA,  0), );
        PH(1, 2, RD_A(1, 2),          STG(gA + 524288, kA,  8192), );
        PH(1, 3, RD_A(1, 3),          STG(gB,          kB,  49152), VM2);
    }

    // epilogue: C/D map col=lane&15, row=(lane>>4)*4+j
#pragma unroll
    for (int n = 0; n < 4; ++n) {
        const int col = n0g + wc * 64 + n * 16 + l15;
        const float bv = bias[col];
#pragma unroll
        for (int m = 0; m < 8; ++m) {
            const int rbase = m0g + wr * 128 + m * 16 + ((lane >> 4) << 2);
#pragma unroll
            for (int j = 0; j < 4; ++j)
                out[(size_t)(rbase + j) * N_DIM + col] = acc[m][n][j] + bv;
        }
    }
}

// ---------------------------------------------------------------------------
extern "C" void kernel_launch(void* const* d_in, const int* in_sizes, int n_in,
                              void* d_out, int out_size, void* d_ws, size_t ws_size,
                              hipStream_t stream) {
    const float* x    = (const float*)d_in[0];  // [2,2048,4096]
    const float* w    = (const float*)d_in[1];  // [4096,4096]
    const float* bias = (const float*)d_in[2];  // [4096]
    const float* sA   = (const float*)d_in[3];  // [4096,4]
    const float* sB   = (const float*)d_in[4];  // [4,4096]
    const float* g    = (const float*)d_in[5];  // [4]
    float* out = (float*)d_out;

    // [weff bf16: 32MB][x_bf16: 32MB][tB f32: 64KB][tAg f32: 64KB]
    __hip_bfloat16* weff = (__hip_bfloat16*)d_ws;
    __hip_bfloat16* xb   = (__hip_bfloat16*)((char*)d_ws + (32ull << 20));
    float* tB  = (float*)((char*)d_ws + (64ull << 20));
    float* tAg = (float*)((char*)d_ws + (64ull << 20) + (R_DIM * K_DIM * 4));

    k_prep<<<dim3((2 * R_DIM * K_DIM) / 256), dim3(256), 0, stream>>>(sA, sB, g, tB, tAg);
    k_xcast<<<dim3((M_DIM * K_DIM) / (256 * 8)), dim3(256), 0, stream>>>(x, xb);
    k_weff<<<dim3(N_DIM), dim3(256), 0, stream>>>(w, tB, tAg, weff);
    k_gemm8<<<dim3((M_DIM / 256) * (N_DIM / 256)), dim3(512), 0, stream>>>(xb, weff, bias, out);
}

// Round 9
// 152.206 us; speedup vs baseline: 1.0501x; 1.0117x over previous
//
#include <hip/hip_runtime.h>
#include <hip/hip_bf16.h>

typedef __attribute__((ext_vector_type(8))) short bf16x8;
typedef __attribute__((ext_vector_type(4))) float f32x4;
typedef __attribute__((ext_vector_type(4))) short s16x4;

#define M_DIM 4096   // B*S = 2*2048
#define N_DIM 4096   // D_out
#define K_DIM 4096   // D_in
#define R_DIM 4

__device__ __forceinline__ short to_bf16(float f) {
    __hip_bfloat16 h = __float2bfloat16(f);
    return *reinterpret_cast<short*>(&h);
}

// ---------------------------------------------------------------------------
// Kernel 1: tB[r][i] = tanh(scale_B[r,i]); tAg[o][r] = tanh(scale_A[o,r])*g[r]
// ---------------------------------------------------------------------------
__global__ __launch_bounds__(256)
void k_prep(const float* __restrict__ sA, const float* __restrict__ sB,
            const float* __restrict__ g, float* __restrict__ tB,
            float* __restrict__ tAg) {
    int i = blockIdx.x * 256 + threadIdx.x;
    if (i < R_DIM * K_DIM) {
        tB[i] = tanhf(sB[i]);
    } else {
        int j = i - R_DIM * K_DIM;   // j = o*4 + r
        tAg[j] = tanhf(sA[j]) * g[j & 3];
    }
}

// ---------------------------------------------------------------------------
// Kernel 2: x_bf16[m,k] = (bf16) x[m,k]
// ---------------------------------------------------------------------------
__global__ __launch_bounds__(256)
void k_xcast(const float* __restrict__ x, __hip_bfloat16* __restrict__ xb) {
    const size_t i = ((size_t)blockIdx.x * 256 + threadIdx.x) << 3;
    float4 u = *(const float4*)&x[i];
    float4 v = *(const float4*)&x[i + 4];
    bf16x8 pk;
    pk[0] = to_bf16(u.x); pk[1] = to_bf16(u.y);
    pk[2] = to_bf16(u.z); pk[3] = to_bf16(u.w);
    pk[4] = to_bf16(v.x); pk[5] = to_bf16(v.y);
    pk[6] = to_bf16(v.z); pk[7] = to_bf16(v.w);
    *(bf16x8*)&xb[i] = pk;
}

// ---------------------------------------------------------------------------
// Kernel 3: W_eff[o,i] = weight[o,i] * sum_r tAg[o,r]*tB[r,i]  -> bf16
// ---------------------------------------------------------------------------
__global__ __launch_bounds__(256)
void k_weff(const float* __restrict__ w, const float* __restrict__ tB,
            const float* __restrict__ tAg, __hip_bfloat16* __restrict__ weff) {
    const int o = blockIdx.x;
    const float a0 = tAg[o * 4 + 0];
    const float a1 = tAg[o * 4 + 1];
    const float a2 = tAg[o * 4 + 2];
    const float a3 = tAg[o * 4 + 3];
#pragma unroll
    for (int it = 0; it < 4; ++it) {
        const int i = (it * 256 + (int)threadIdx.x) << 2;
        float4 wv = *(const float4*)&w[(size_t)o * K_DIM + i];
        float4 b0 = *(const float4*)&tB[0 * K_DIM + i];
        float4 b1 = *(const float4*)&tB[1 * K_DIM + i];
        float4 b2 = *(const float4*)&tB[2 * K_DIM + i];
        float4 b3 = *(const float4*)&tB[3 * K_DIM + i];
        float s0 = a0 * b0.x + a1 * b1.x + a2 * b2.x + a3 * b3.x;
        float s1 = a0 * b0.y + a1 * b1.y + a2 * b2.y + a3 * b3.y;
        float s2 = a0 * b0.z + a1 * b1.z + a2 * b2.z + a3 * b3.z;
        float s3 = a0 * b0.w + a1 * b1.w + a2 * b2.w + a3 * b3.w;
        s16x4 pk;
        pk[0] = to_bf16(wv.x * s0);
        pk[1] = to_bf16(wv.y * s1);
        pk[2] = to_bf16(wv.z * s2);
        pk[3] = to_bf16(wv.w * s3);
        *(s16x4*)&weff[(size_t)o * K_DIM + i] = pk;
    }
}

// ---------------------------------------------------------------------------
// Kernel 4: out = x_bf16 @ weff^T + bias — 256x256, 4 MERGED phases per
// 2-K-tile iteration (half the barriers of round 8), A TRIPLE-buffered.
// LDS = 3x32K A + 2x32K B = 160 KiB.  Layout/swizzle/staging byte-identical
// to round 8 per buffer; only buffer bases changed.
//
// Phase = { reads (8 A-frag b128 [+8 B at F1/F3]); stage 1 FULL tile
// (4 gload_lds); [vmcnt(4) @F2,F4]; s_barrier; lgkmcnt(0); sched_barrier(0);
// setprio(1) 32 MFMA (16 ks0 then 16 ks1 — indep within each half)
// setprio(0) }.
//
// Iter (K-tiles t=2i, t+1; A-bufs u=t%3, v=(t+1)%3, w=(t+2)%3):
//   F1: read A[u] q01 + B[t%2=0];  stage B[1] <- tile t+1
//   F2: read A[u] q23;             stage A[w] <- tile t+2;  VM4
//   F3: read A[v] q01 + B[1];      stage B[0] <- tile t+2
//   F4: read A[v] q23;             stage A[u] <- tile t+3;  VM4
// Ledger (all gaps >= 2 phases):
//   A[w]<-t+2 @F2: old tile t-1 last read F4(prev) -> gap 2; read F1' -> gap 3
//   A[u]<-t+3 @F4: old tile t last read F2 -> gap 2; read F3' -> gap 3
//   B[1]<-t+1 @F1: old tile t-1 read F3(prev) -> gap 2; read F3 -> gap 2
//   B[0]<-t+2 @F3: old tile t read F1 -> gap 2; read F1' -> gap 2
// FIFO/vmcnt(4): steady in-flight after each VM = 1 tile (4 loads);
//   VM@F2 completes {A-stage F4(prev), B-stage F1} (exactly F3's needs);
//   VM@F4 completes {A-stage F2, B-stage F3} (exactly F1''s needs).
// A rotation period 3 -> main loop unrolled x3 (6 K-tiles / body).
// ---------------------------------------------------------------------------
#define MFMA(A, B, C) __builtin_amdgcn_mfma_f32_16x16x32_bf16(A, B, C, 0, 0, 0)

// byte bases for reads
#define RA0 0
#define RA1 32768
#define RA2 65536
// short bases for staging
#define SA0 0
#define SA1 16384
#define SA2 32768
#define SB0 49152
#define SB1 65536

#define RD_A8(ab, qq) \
    aA = *(const bf16x8*)(LA0 + (ab) + (qq)*4096 + 0); \
    aB = *(const bf16x8*)(LA1 + (ab) + (qq)*4096 + 0); \
    aC = *(const bf16x8*)(LA0 + (ab) + (qq)*4096 + 2048); \
    aD = *(const bf16x8*)(LA1 + (ab) + (qq)*4096 + 2048); \
    aE = *(const bf16x8*)(LA0 + (ab) + (qq)*4096 + 4096); \
    aF = *(const bf16x8*)(LA1 + (ab) + (qq)*4096 + 4096); \
    aG = *(const bf16x8*)(LA0 + (ab) + (qq)*4096 + 6144); \
    aH = *(const bf16x8*)(LA1 + (ab) + (qq)*4096 + 6144);

#define RD_B8(bb) \
    b0 = *(const bf16x8*)(LB0 + (bb) + 0);    b1 = *(const bf16x8*)(LB1 + (bb) + 0); \
    b2 = *(const bf16x8*)(LB0 + (bb) + 2048); b3 = *(const bf16x8*)(LB1 + (bb) + 2048); \
    b4 = *(const bf16x8*)(LB0 + (bb) + 4096); b5 = *(const bf16x8*)(LB1 + (bb) + 4096); \
    b6 = *(const bf16x8*)(LB0 + (bb) + 6144); b7 = *(const bf16x8*)(LB1 + (bb) + 6144);

#define MFMA32(qq) \
    /* ks0: 16 independent (each acc touched once) */ \
    acc[2*(qq)+0][0] = MFMA(aA, b0, acc[2*(qq)+0][0]); \
    acc[2*(qq)+0][1] = MFMA(aA, b2, acc[2*(qq)+0][1]); \
    acc[2*(qq)+0][2] = MFMA(aA, b4, acc[2*(qq)+0][2]); \
    acc[2*(qq)+0][3] = MFMA(aA, b6, acc[2*(qq)+0][3]); \
    acc[2*(qq)+1][0] = MFMA(aC, b0, acc[2*(qq)+1][0]); \
    acc[2*(qq)+1][1] = MFMA(aC, b2, acc[2*(qq)+1][1]); \
    acc[2*(qq)+1][2] = MFMA(aC, b4, acc[2*(qq)+1][2]); \
    acc[2*(qq)+1][3] = MFMA(aC, b6, acc[2*(qq)+1][3]); \
    acc[2*(qq)+2][0] = MFMA(aE, b0, acc[2*(qq)+2][0]); \
    acc[2*(qq)+2][1] = MFMA(aE, b2, acc[2*(qq)+2][1]); \
    acc[2*(qq)+2][2] = MFMA(aE, b4, acc[2*(qq)+2][2]); \
    acc[2*(qq)+2][3] = MFMA(aE, b6, acc[2*(qq)+2][3]); \
    acc[2*(qq)+3][0] = MFMA(aG, b0, acc[2*(qq)+3][0]); \
    acc[2*(qq)+3][1] = MFMA(aG, b2, acc[2*(qq)+3][1]); \
    acc[2*(qq)+3][2] = MFMA(aG, b4, acc[2*(qq)+3][2]); \
    acc[2*(qq)+3][3] = MFMA(aG, b6, acc[2*(qq)+3][3]); \
    /* ks1: partners, >=16 issue slots after dependency */ \
    acc[2*(qq)+0][0] = MFMA(aB, b1, acc[2*(qq)+0][0]); \
    acc[2*(qq)+0][1] = MFMA(aB, b3, acc[2*(qq)+0][1]); \
    acc[2*(qq)+0][2] = MFMA(aB, b5, acc[2*(qq)+0][2]); \
    acc[2*(qq)+0][3] = MFMA(aB, b7, acc[2*(qq)+0][3]); \
    acc[2*(qq)+1][0] = MFMA(aD, b1, acc[2*(qq)+1][0]); \
    acc[2*(qq)+1][1] = MFMA(aD, b3, acc[2*(qq)+1][1]); \
    acc[2*(qq)+1][2] = MFMA(aD, b5, acc[2*(qq)+1][2]); \
    acc[2*(qq)+1][3] = MFMA(aD, b7, acc[2*(qq)+1][3]); \
    acc[2*(qq)+2][0] = MFMA(aF, b1, acc[2*(qq)+2][0]); \
    acc[2*(qq)+2][1] = MFMA(aF, b3, acc[2*(qq)+2][1]); \
    acc[2*(qq)+2][2] = MFMA(aF, b5, acc[2*(qq)+2][2]); \
    acc[2*(qq)+2][3] = MFMA(aF, b7, acc[2*(qq)+2][3]); \
    acc[2*(qq)+3][0] = MFMA(aH, b1, acc[2*(qq)+3][0]); \
    acc[2*(qq)+3][1] = MFMA(aH, b3, acc[2*(qq)+3][1]); \
    acc[2*(qq)+3][2] = MFMA(aH, b5, acc[2*(qq)+3][2]); \
    acc[2*(qq)+3][3] = MFMA(aH, b7, acc[2*(qq)+3][3]);

#define VM4 asm volatile("s_waitcnt vmcnt(4)" ::: "memory")

#define PH4(READS_STMT, STAGE_STMT, VM_STMT, qq) \
    { READS_STMT; \
      STAGE_STMT; \
      VM_STMT; \
      __builtin_amdgcn_s_barrier(); \
      asm volatile("s_waitcnt lgkmcnt(0)" ::: "memory"); \
      __builtin_amdgcn_sched_barrier(0); \
      __builtin_amdgcn_s_setprio(1); \
      MFMA32(qq); \
      __builtin_amdgcn_s_setprio(0); }

// one 2-K-tile iteration; RAu/RAv = read bufs (bytes), SAu/SAw = stage dsts
// (shorts), KT1..KT3 = element k-offsets of tiles t+1, t+2, t+3
#define ITER4(RAu, RAv, SAu, SAw, KT1, KT2, KT3) \
    PH4(RD_A8(RAu, 0); RD_B8(0),     STGT(gB, KT1, SB1), , 0) \
    PH4(RD_A8(RAu, 2),               STGT(gA, KT2, SAw), VM4, 2) \
    PH4(RD_A8(RAv, 0); RD_B8(32768), STGT(gB, KT2, SB0), , 0) \
    PH4(RD_A8(RAv, 2),               STGT(gA, KT3, SAu), VM4, 2)

__global__ __launch_bounds__(512, 2)
void k_gemm8(const __hip_bfloat16* __restrict__ xb,
             const __hip_bfloat16* __restrict__ weff,
             const float* __restrict__ bias, float* __restrict__ out) {
    __shared__ short lds[81920];   // 160 KiB: A0/A1/A2 @ 0/32768/65536 B; B0/B1 @ 98304/131072 B

    const int tid  = threadIdx.x;
    const int lane = tid & 63;
    const int wid  = tid >> 6;
    const int wr   = wid >> 2;           // wave M row 0..1  (128 rows each)
    const int wc   = wid & 3;            // wave N col 0..3  (64 cols each)
    const int l15  = lane & 15;
    const int cb0  = (lane >> 4) << 4;   // ksub0 fragment col-byte (bits 4-5)

    // XCD-aware bijective swizzle: nwg=256, 256 % 8 == 0
    const int bid = blockIdx.x;
    const int swz = (bid & 7) * 32 + (bid >> 3);
    const int m0g = (swz >> 4) << 8;
    const int n0g = (swz & 15) << 8;

    // per-lane LDS fragment base pointers (round-8 verified swizzle folding:
    // rows used are (mult of 8)+l15 -> mask lane-constant; cb bits 4-6, no carries)
    const int mask = (l15 & 7) << 4;
    const int cbs0 = cb0 ^ mask;
    const int cbs1 = (cb0 + 64) ^ mask;
    const char* LAb = (const char*)lds + wr * 16384 + l15 * 128;
    const char* LA0 = LAb + cbs0;
    const char* LA1 = LAb + cbs1;
    const char* LBb = (const char*)lds + 98304 + (wc >> 1) * 16384 +
                      ((wc & 1) * 64 + l15) * 128;
    const char* LB0 = LBb + cbs0;
    const char* LB1 = LBb + cbs1;

    // per-lane global staging base pointers (inverse-swizzled source)
    const int rowL  = tid >> 3;               // 0..63
    const int colbL = ((tid * 16) & 127) ^ ((rowL & 7) << 4);
    const __hip_bfloat16* gA = xb   + ((size_t)(m0g + rowL) << 12) + (colbL >> 1);
    const __hip_bfloat16* gB = weff + ((size_t)(n0g + rowL) << 12) + (colbL >> 1);

    // stage one FULL 256x64 tile (4 x gload_lds, 64 rows each)
    auto STGT = [&](const __hip_bfloat16* gbase, int k0, int dstShort) {
#pragma unroll
        for (int p = 0; p < 4; ++p) {
            __builtin_amdgcn_global_load_lds(
                (const __attribute__((address_space(1))) void*)(gbase + p * 262144 + k0),
                (__attribute__((address_space(3))) void*)&lds[dstShort + p * 4096 + tid * 8],
                16, 0, 0);
        }
    };

    f32x4 acc[8][4] = {};
    bf16x8 aA, aB, aC, aD, aE, aF, aG, aH;
    bf16x8 b0, b1, b2, b3, b4, b5, b6, b7;

    // prologue: B[0]<-t0, A[0]<-t0, A[1]<-t1 (12 loads), full drain
    STGT(gB, 0, SB0);
    STGT(gA, 0, SA0);
    STGT(gA, 64, SA1);
    asm volatile("s_waitcnt vmcnt(0)" ::: "memory");
    __builtin_amdgcn_s_barrier();
    __builtin_amdgcn_sched_barrier(0);

    // main loop: 3 iters (6 K-tiles) per body; A-buf rotation period 3
    for (int j = 0; j < 10; ++j) {
        const int t = 6 * j;
        ITER4(RA0, RA1, SA0, SA2, (t + 1) * 64, (t + 2) * 64, (t + 3) * 64);
        ITER4(RA2, RA0, SA2, SA1, (t + 3) * 64, (t + 4) * 64, (t + 5) * 64);
        ITER4(RA1, RA2, SA1, SA0, (t + 5) * 64, (t + 6) * 64, (t + 7) * 64);
    }
    // tail: K-tiles 60..63 (stage k clamped to tile 63; dead stages proven safe)
    ITER4(RA0, RA1, SA0, SA2, 61 * 64, 62 * 64, 63 * 64);
    ITER4(RA2, RA0, SA2, SA1, 63 * 64, 63 * 64, 63 * 64);

    // epilogue: C/D map col=lane&15, row=(lane>>4)*4+j
#pragma unroll
    for (int n = 0; n < 4; ++n) {
        const int col = n0g + wc * 64 + n * 16 + l15;
        const float bv = bias[col];
#pragma unroll
        for (int m = 0; m < 8; ++m) {
            const int rbase = m0g + wr * 128 + m * 16 + ((lane >> 4) << 2);
#pragma unroll
            for (int j2 = 0; j2 < 4; ++j2)
                out[(size_t)(rbase + j2) * N_DIM + col] = acc[m][n][j2] + bv;
        }
    }
}

// ---------------------------------------------------------------------------
extern "C" void kernel_launch(void* const* d_in, const int* in_sizes, int n_in,
                              void* d_out, int out_size, void* d_ws, size_t ws_size,
                              hipStream_t stream) {
    const float* x    = (const float*)d_in[0];  // [2,2048,4096]
    const float* w    = (const float*)d_in[1];  // [4096,4096]
    const float* bias = (const float*)d_in[2];  // [4096]
    const float* sA   = (const float*)d_in[3];  // [4096,4]
    const float* sB   = (const float*)d_in[4];  // [4,4096]
    const float* g    = (const float*)d_in[5];  // [4]
    float* out = (float*)d_out;

    // [weff bf16: 32MB][x_bf16: 32MB][tB f32: 64KB][tAg f32: 64KB]
    __hip_bfloat16* weff = (__hip_bfloat16*)d_ws;
    __hip_bfloat16* xb   = (__hip_bfloat16*)((char*)d_ws + (32ull << 20));
    float* tB  = (float*)((char*)d_ws + (64ull << 20));
    float* tAg = (float*)((char*)d_ws + (64ull << 20) + (R_DIM * K_DIM * 4));

    k_prep<<<dim3((2 * R_DIM * K_DIM) / 256), dim3(256), 0, stream>>>(sA, sB, g, tB, tAg);
    k_xcast<<<dim3((M_DIM * K_DIM) / (256 * 8)), dim3(256), 0, stream>>>(x, xb);
    k_weff<<<dim3(N_DIM), dim3(256), 0, stream>>>(w, tB, tAg, weff);
    k_gemm8<<<dim3((M_DIM / 256) * (N_DIM / 256)), dim3(512), 0, stream>>>(xb, weff, bias, out);
}

// Round 10
// 148.568 us; speedup vs baseline: 1.0759x; 1.0245x over previous
//
#include <hip/hip_runtime.h>
#include <hip/hip_bf16.h>

typedef __attribute__((ext_vector_type(8))) short bf16x8;
typedef __attribute__((ext_vector_type(4))) float f32x4;
typedef __attribute__((ext_vector_type(4))) short s16x4;

#define M_DIM 4096   // B*S = 2*2048
#define N_DIM 4096   // D_out
#define K_DIM 4096   // D_in
#define R_DIM 4

__device__ __forceinline__ short to_bf16(float f) {
    __hip_bfloat16 h = __float2bfloat16(f);
    return *reinterpret_cast<short*>(&h);
}

// ---------------------------------------------------------------------------
// Kernel 1: tB[r][i] = tanh(scale_B[r,i]); tAg[o][r] = tanh(scale_A[o,r])*g[r]
// ---------------------------------------------------------------------------
__global__ __launch_bounds__(256)
void k_prep(const float* __restrict__ sA, const float* __restrict__ sB,
            const float* __restrict__ g, float* __restrict__ tB,
            float* __restrict__ tAg) {
    int i = blockIdx.x * 256 + threadIdx.x;
    if (i < R_DIM * K_DIM) {
        tB[i] = tanhf(sB[i]);
    } else {
        int j = i - R_DIM * K_DIM;   // j = o*4 + r
        tAg[j] = tanhf(sA[j]) * g[j & 3];
    }
}

// ---------------------------------------------------------------------------
// Kernel 2 (merged): blocks [0,8192): x_bf16 cast; blocks [8192,12288):
// W_eff row computation.  Both pure-BW, independent — one launch.
// ---------------------------------------------------------------------------
__global__ __launch_bounds__(256)
void k_pre2(const float* __restrict__ x, __hip_bfloat16* __restrict__ xb,
            const float* __restrict__ w, const float* __restrict__ tB,
            const float* __restrict__ tAg, __hip_bfloat16* __restrict__ weff) {
    const int bid = blockIdx.x;
    if (bid < 8192) {
        const size_t i = ((size_t)bid * 256 + threadIdx.x) << 3;
        float4 u = *(const float4*)&x[i];
        float4 v = *(const float4*)&x[i + 4];
        bf16x8 pk;
        pk[0] = to_bf16(u.x); pk[1] = to_bf16(u.y);
        pk[2] = to_bf16(u.z); pk[3] = to_bf16(u.w);
        pk[4] = to_bf16(v.x); pk[5] = to_bf16(v.y);
        pk[6] = to_bf16(v.z); pk[7] = to_bf16(v.w);
        *(bf16x8*)&xb[i] = pk;
    } else {
        const int o = bid - 8192;
        const float a0 = tAg[o * 4 + 0];
        const float a1 = tAg[o * 4 + 1];
        const float a2 = tAg[o * 4 + 2];
        const float a3 = tAg[o * 4 + 3];
#pragma unroll
        for (int it = 0; it < 4; ++it) {
            const int i = (it * 256 + (int)threadIdx.x) << 2;
            float4 wv = *(const float4*)&w[(size_t)o * K_DIM + i];
            float4 b0 = *(const float4*)&tB[0 * K_DIM + i];
            float4 b1 = *(const float4*)&tB[1 * K_DIM + i];
            float4 b2 = *(const float4*)&tB[2 * K_DIM + i];
            float4 b3 = *(const float4*)&tB[3 * K_DIM + i];
            float s0 = a0 * b0.x + a1 * b1.x + a2 * b2.x + a3 * b3.x;
            float s1 = a0 * b0.y + a1 * b1.y + a2 * b2.y + a3 * b3.y;
            float s2 = a0 * b0.z + a1 * b1.z + a2 * b2.z + a3 * b3.z;
            float s3 = a0 * b0.w + a1 * b1.w + a2 * b2.w + a3 * b3.w;
            s16x4 pk;
            pk[0] = to_bf16(wv.x * s0);
            pk[1] = to_bf16(wv.y * s1);
            pk[2] = to_bf16(wv.z * s2);
            pk[3] = to_bf16(wv.w * s3);
            *(s16x4*)&weff[(size_t)o * K_DIM + i] = pk;
        }
    }
}

// ---------------------------------------------------------------------------
// Kernel 3: out = x_bf16 @ weff^T + bias — round-9 verified 4-merged-phase
// schedule, A tri-buffered, 160 KiB LDS.  This round: counted lgkmcnt split
// inside each phase (reads issued in two pinned groups; lgkm(N) -> ks0 MFMAs
// -> lgkm(0) -> ks1 MFMAs; sched_barrier(0) after each counted wait, rule 18).
// Stage slots / vmcnt geometry / ledger byte-identical to round 9.
// ---------------------------------------------------------------------------
#define MFMA(A, B, C) __builtin_amdgcn_mfma_f32_16x16x32_bf16(A, B, C, 0, 0, 0)

#define RA0 0
#define RA1 32768
#define RA2 65536
#define SA0 0
#define SA1 16384
#define SA2 32768
#define SB0 49152
#define SB1 65536

// read groups: ks0 = cbs0-column regs, ks1 = cbs1-column regs
#define RD_A_KS0(ab, qq) \
    aA = *(const bf16x8*)(LA0 + (ab) + (qq)*4096 + 0); \
    aC = *(const bf16x8*)(LA0 + (ab) + (qq)*4096 + 2048); \
    aE = *(const bf16x8*)(LA0 + (ab) + (qq)*4096 + 4096); \
    aG = *(const bf16x8*)(LA0 + (ab) + (qq)*4096 + 6144);

#define RD_A_KS1(ab, qq) \
    aB = *(const bf16x8*)(LA1 + (ab) + (qq)*4096 + 0); \
    aD = *(const bf16x8*)(LA1 + (ab) + (qq)*4096 + 2048); \
    aF = *(const bf16x8*)(LA1 + (ab) + (qq)*4096 + 4096); \
    aH = *(const bf16x8*)(LA1 + (ab) + (qq)*4096 + 6144);

#define RD_B_KS0(bb) \
    b0 = *(const bf16x8*)(LB0 + (bb) + 0); \
    b2 = *(const bf16x8*)(LB0 + (bb) + 2048); \
    b4 = *(const bf16x8*)(LB0 + (bb) + 4096); \
    b6 = *(const bf16x8*)(LB0 + (bb) + 6144);

#define RD_B_KS1(bb) \
    b1 = *(const bf16x8*)(LB1 + (bb) + 0); \
    b3 = *(const bf16x8*)(LB1 + (bb) + 2048); \
    b5 = *(const bf16x8*)(LB1 + (bb) + 4096); \
    b7 = *(const bf16x8*)(LB1 + (bb) + 6144);

#define MFMA16_KS0(qq) \
    acc[2*(qq)+0][0] = MFMA(aA, b0, acc[2*(qq)+0][0]); \
    acc[2*(qq)+0][1] = MFMA(aA, b2, acc[2*(qq)+0][1]); \
    acc[2*(qq)+0][2] = MFMA(aA, b4, acc[2*(qq)+0][2]); \
    acc[2*(qq)+0][3] = MFMA(aA, b6, acc[2*(qq)+0][3]); \
    acc[2*(qq)+1][0] = MFMA(aC, b0, acc[2*(qq)+1][0]); \
    acc[2*(qq)+1][1] = MFMA(aC, b2, acc[2*(qq)+1][1]); \
    acc[2*(qq)+1][2] = MFMA(aC, b4, acc[2*(qq)+1][2]); \
    acc[2*(qq)+1][3] = MFMA(aC, b6, acc[2*(qq)+1][3]); \
    acc[2*(qq)+2][0] = MFMA(aE, b0, acc[2*(qq)+2][0]); \
    acc[2*(qq)+2][1] = MFMA(aE, b2, acc[2*(qq)+2][1]); \
    acc[2*(qq)+2][2] = MFMA(aE, b4, acc[2*(qq)+2][2]); \
    acc[2*(qq)+2][3] = MFMA(aE, b6, acc[2*(qq)+2][3]); \
    acc[2*(qq)+3][0] = MFMA(aG, b0, acc[2*(qq)+3][0]); \
    acc[2*(qq)+3][1] = MFMA(aG, b2, acc[2*(qq)+3][1]); \
    acc[2*(qq)+3][2] = MFMA(aG, b4, acc[2*(qq)+3][2]); \
    acc[2*(qq)+3][3] = MFMA(aG, b6, acc[2*(qq)+3][3]);

#define MFMA16_KS1(qq) \
    acc[2*(qq)+0][0] = MFMA(aB, b1, acc[2*(qq)+0][0]); \
    acc[2*(qq)+0][1] = MFMA(aB, b3, acc[2*(qq)+0][1]); \
    acc[2*(qq)+0][2] = MFMA(aB, b5, acc[2*(qq)+0][2]); \
    acc[2*(qq)+0][3] = MFMA(aB, b7, acc[2*(qq)+0][3]); \
    acc[2*(qq)+1][0] = MFMA(aD, b1, acc[2*(qq)+1][0]); \
    acc[2*(qq)+1][1] = MFMA(aD, b3, acc[2*(qq)+1][1]); \
    acc[2*(qq)+1][2] = MFMA(aD, b5, acc[2*(qq)+1][2]); \
    acc[2*(qq)+1][3] = MFMA(aD, b7, acc[2*(qq)+1][3]); \
    acc[2*(qq)+2][0] = MFMA(aF, b1, acc[2*(qq)+2][0]); \
    acc[2*(qq)+2][1] = MFMA(aF, b3, acc[2*(qq)+2][1]); \
    acc[2*(qq)+2][2] = MFMA(aF, b5, acc[2*(qq)+2][2]); \
    acc[2*(qq)+2][3] = MFMA(aF, b7, acc[2*(qq)+2][3]); \
    acc[2*(qq)+3][0] = MFMA(aH, b1, acc[2*(qq)+3][0]); \
    acc[2*(qq)+3][1] = MFMA(aH, b3, acc[2*(qq)+3][1]); \
    acc[2*(qq)+3][2] = MFMA(aH, b5, acc[2*(qq)+3][2]); \
    acc[2*(qq)+3][3] = MFMA(aH, b7, acc[2*(qq)+3][3]);

#define VM4 asm volatile("s_waitcnt vmcnt(4)" ::: "memory")
#define SB0F __builtin_amdgcn_sched_barrier(0)

// phase with split waits; LGKN = outstanding count after ks0 group completes
#define PH4(RD_KS0, RD_KS1, STAGE_STMT, VM_STMT, qq, LGK_ASM) \
    { RD_KS0; \
      SB0F; \
      RD_KS1; \
      STAGE_STMT; \
      VM_STMT; \
      __builtin_amdgcn_s_barrier(); \
      asm volatile(LGK_ASM ::: "memory"); \
      SB0F; \
      __builtin_amdgcn_s_setprio(1); \
      MFMA16_KS0(qq); \
      __builtin_amdgcn_s_setprio(0); \
      asm volatile("s_waitcnt lgkmcnt(0)" ::: "memory"); \
      SB0F; \
      __builtin_amdgcn_s_setprio(1); \
      MFMA16_KS1(qq); \
      __builtin_amdgcn_s_setprio(0); }

// one 2-K-tile iteration (slots/ledger = round 9, verified)
#define ITER4(RAu, RAv, SAu, SAw, KT1, KT2, KT3) \
    PH4(RD_A_KS0(RAu, 0); RD_B_KS0(0), RD_A_KS1(RAu, 0); RD_B_KS1(0), \
        STGT(gB, KT1, SB1), , 0, "s_waitcnt lgkmcnt(8)") \
    PH4(RD_A_KS0(RAu, 2), RD_A_KS1(RAu, 2), \
        STGT(gA, KT2, SAw), VM4, 2, "s_waitcnt lgkmcnt(4)") \
    PH4(RD_A_KS0(RAv, 0); RD_B_KS0(32768), RD_A_KS1(RAv, 0); RD_B_KS1(32768), \
        STGT(gB, KT2, SB0), , 0, "s_waitcnt lgkmcnt(8)") \
    PH4(RD_A_KS0(RAv, 2), RD_A_KS1(RAv, 2), \
        STGT(gA, KT3, SAu), VM4, 2, "s_waitcnt lgkmcnt(4)")

__global__ __launch_bounds__(512, 2)
void k_gemm8(const __hip_bfloat16* __restrict__ xb,
             const __hip_bfloat16* __restrict__ weff,
             const float* __restrict__ bias, float* __restrict__ out) {
    __shared__ short lds[81920];   // A0/A1/A2 @ 0/32768/65536 B; B0/B1 @ 98304/131072 B

    const int tid  = threadIdx.x;
    const int lane = tid & 63;
    const int wid  = tid >> 6;
    const int wr   = wid >> 2;
    const int wc   = wid & 3;
    const int l15  = lane & 15;
    const int cb0  = (lane >> 4) << 4;

    const int bid = blockIdx.x;
    const int swz = (bid & 7) * 32 + (bid >> 3);
    const int m0g = (swz >> 4) << 8;
    const int n0g = (swz & 15) << 8;

    const int mask = (l15 & 7) << 4;
    const int cbs0 = cb0 ^ mask;
    const int cbs1 = (cb0 + 64) ^ mask;
    const char* LAb = (const char*)lds + wr * 16384 + l15 * 128;
    const char* LA0 = LAb + cbs0;
    const char* LA1 = LAb + cbs1;
    const char* LBb = (const char*)lds + 98304 + (wc >> 1) * 16384 +
                      ((wc & 1) * 64 + l15) * 128;
    const char* LB0 = LBb + cbs0;
    const char* LB1 = LBb + cbs1;

    const int rowL  = tid >> 3;
    const int colbL = ((tid * 16) & 127) ^ ((rowL & 7) << 4);
    const __hip_bfloat16* gA = xb   + ((size_t)(m0g + rowL) << 12) + (colbL >> 1);
    const __hip_bfloat16* gB = weff + ((size_t)(n0g + rowL) << 12) + (colbL >> 1);

    auto STGT = [&](const __hip_bfloat16* gbase, int k0, int dstShort) {
#pragma unroll
        for (int p = 0; p < 4; ++p) {
            __builtin_amdgcn_global_load_lds(
                (const __attribute__((address_space(1))) void*)(gbase + p * 262144 + k0),
                (__attribute__((address_space(3))) void*)&lds[dstShort + p * 4096 + tid * 8],
                16, 0, 0);
        }
    };

    f32x4 acc[8][4] = {};
    bf16x8 aA, aB, aC, aD, aE, aF, aG, aH;
    bf16x8 b0, b1, b2, b3, b4, b5, b6, b7;

    // prologue: B[0]<-t0, A[0]<-t0, A[1]<-t1, full drain
    STGT(gB, 0, SB0);
    STGT(gA, 0, SA0);
    STGT(gA, 64, SA1);
    asm volatile("s_waitcnt vmcnt(0)" ::: "memory");
    __builtin_amdgcn_s_barrier();
    SB0F;

    for (int j = 0; j < 10; ++j) {
        const int t = 6 * j;
        ITER4(RA0, RA1, SA0, SA2, (t + 1) * 64, (t + 2) * 64, (t + 3) * 64);
        ITER4(RA2, RA0, SA2, SA1, (t + 3) * 64, (t + 4) * 64, (t + 5) * 64);
        ITER4(RA1, RA2, SA1, SA0, (t + 5) * 64, (t + 6) * 64, (t + 7) * 64);
    }
    ITER4(RA0, RA1, SA0, SA2, 61 * 64, 62 * 64, 63 * 64);
    ITER4(RA2, RA0, SA2, SA1, 63 * 64, 63 * 64, 63 * 64);

    // epilogue: C/D map col=lane&15, row=(lane>>4)*4+j
#pragma unroll
    for (int n = 0; n < 4; ++n) {
        const int col = n0g + wc * 64 + n * 16 + l15;
        const float bv = bias[col];
#pragma unroll
        for (int m = 0; m < 8; ++m) {
            const int rbase = m0g + wr * 128 + m * 16 + ((lane >> 4) << 2);
#pragma unroll
            for (int j2 = 0; j2 < 4; ++j2)
                out[(size_t)(rbase + j2) * N_DIM + col] = acc[m][n][j2] + bv;
        }
    }
}

// ---------------------------------------------------------------------------
extern "C" void kernel_launch(void* const* d_in, const int* in_sizes, int n_in,
                              void* d_out, int out_size, void* d_ws, size_t ws_size,
                              hipStream_t stream) {
    const float* x    = (const float*)d_in[0];  // [2,2048,4096]
    const float* w    = (const float*)d_in[1];  // [4096,4096]
    const float* bias = (const float*)d_in[2];  // [4096]
    const float* sA   = (const float*)d_in[3];  // [4096,4]
    const float* sB   = (const float*)d_in[4];  // [4,4096]
    const float* g    = (const float*)d_in[5];  // [4]
    float* out = (float*)d_out;

    // [weff bf16: 32MB][x_bf16: 32MB][tB f32: 64KB][tAg f32: 64KB]
    __hip_bfloat16* weff = (__hip_bfloat16*)d_ws;
    __hip_bfloat16* xb   = (__hip_bfloat16*)((char*)d_ws + (32ull << 20));
    float* tB  = (float*)((char*)d_ws + (64ull << 20));
    float* tAg = (float*)((char*)d_ws + (64ull << 20) + (R_DIM * K_DIM * 4));

    k_prep<<<dim3((2 * R_DIM * K_DIM) / 256), dim3(256), 0, stream>>>(sA, sB, g, tB, tAg);
    k_pre2<<<dim3(8192 + N_DIM), dim3(256), 0, stream>>>(x, xb, w, tB, tAg, weff);
    k_gemm8<<<dim3((M_DIM / 256) * (N_DIM / 256)), dim3(512), 0, stream>>>(xb, weff, bias, out);
}